// Round 2
// baseline (282.968 us; speedup 1.0000x reference)
//
#include <hip/hip_runtime.h>

typedef float f32x4 __attribute__((ext_vector_type(4)));
typedef float f32x2 __attribute__((ext_vector_type(2)));
typedef short bf16x8 __attribute__((ext_vector_type(8)));
typedef short s16x4 __attribute__((ext_vector_type(4)));

#define N_TOT 8192
#define L_OBS 20
#define P_PRED 30
#define E_DIM 64
#define H_DIM 128
#define C_DIM 2048
#define G_DIM 512
#define M_ROWS 16
#define NTH 512
#define A_PAD 200   // shorts per row (400 B, 16B-aligned rows for b128)

#define K1 1.442695041f
#define K2 2.885390082f

static __device__ __forceinline__ unsigned short f2bf(float f) {
  union { float f; unsigned int u; } v; v.f = f;
  unsigned int u = v.u;
  return (unsigned short)((u + 0x7FFFu + ((u >> 16) & 1u)) >> 16);
}
static __device__ __forceinline__ float bf2f(unsigned short b) {
  union { unsigned int u; float f; } v; v.u = ((unsigned int)b) << 16;
  return v.f;
}
// native transcendentals (avoid IEEE div sequence; no fast-math flags needed)
static __device__ __forceinline__ float ex2(float x)  { float r; asm("v_exp_f32 %0, %1" : "=v"(r) : "v"(x)); return r; }
static __device__ __forceinline__ float rcpn(float x) { float r; asm("v_rcp_f32 %0, %1" : "=v"(r) : "v"(x)); return r; }

__global__ __launch_bounds__(NTH, 4)
void lstm_traj(const float* __restrict__ img,      // [N][C]
               const float* __restrict__ obs_pos,  // [N][L][2]
               const float* __restrict__ obs_rel,  // [N][L][2]
               const int*   __restrict__ hist,     // [N]
               const float* __restrict__ h0,       // [H]
               const float* __restrict__ W_embed,  // [2][E]
               const float* __restrict__ b_embed,  // [E]
               const float* __restrict__ W_ih,     // [E][4H]
               const float* __restrict__ W_hh,     // [H][4H]
               const float* __restrict__ b_ih,     // [4H]
               const float* __restrict__ b_hh,     // [4H]
               const float* __restrict__ W_pred,   // [H+C][2]
               const float* __restrict__ b_pred,   // [2]
               float* __restrict__ out)            // [N][P][2]
{
  __shared__ unsigned short A_lds[2][M_ROWS][A_PAD]; // [e(64) | h(128) | pad]
  __shared__ float We_lds[2][E_DIM];
  __shared__ float be_lds[E_DIM];
  __shared__ float Wp_lds[H_DIM][2];

  const int t    = threadIdx.x;
  const int w    = t >> 6;       // wave 0..7
  const int l    = t & 63;
  const int u15  = l & 15;       // MFMA A-row / D-col index
  const int rq   = l >> 4;       // MFMA k-group / row-quad
  const int u    = w * 16 + u15; // owned hidden unit 0..127
  const int wg0  = blockIdx.x * M_ROWS;
  const int grow = t >> 5;       // 0..15: row for e/rel/img work
  const int c2   = t & 31;       // 0..31: slot within row group

  // ---- stage small weights to LDS ----
  if (t < 128) We_lds[t >> 6][t & 63] = W_embed[t];
  if (t < 64)  be_lds[t] = b_embed[t];
  if (t >= 128 && t < 384) ((float*)Wp_lds)[t - 128] = W_pred[t - 128];

  // ---- state init + A_lds[0] h-part ----
  const float h0u = h0[u];
  const unsigned short h0b = f2bf(h0u);
  float cs[4];
  unsigned short hb[4];
  int sact = 0;  // packed per-q first-active-step (20 - hist)
#pragma unroll
  for (int q = 0; q < 4; ++q) {
    const int row = rq * 4 + q;
    cs[q] = h0u; hb[q] = h0b;
    A_lds[0][row][64 + u] = h0b;
    const int sa = 20 - hist[wg0 + row];   // 1..20
    sact |= (sa & 255) << (8 * q);
  }
  int mn = 20;
#pragma unroll
  for (int q = 0; q < 4; ++q) { const int sa = (sact >> (8 * q)) & 255; mn = sa < mn ? sa : mn; }
  { int o = __shfl_xor(mn, 16); mn = o < mn ? o : mn; }
  { int o = __shfl_xor(mn, 32); mn = o < mn ? o : mn; }
  const int s_min = __builtin_amdgcn_readfirstlane(mn < 1 ? 1 : mn);

  // ---- B fragments (weights) in registers: 24 frags = 96 VGPR ----
  bf16x8 B[4][6];
#pragma unroll
  for (int ks = 0; ks < 6; ++ks)
#pragma unroll
    for (int i = 0; i < 8; ++i) {
      const int k = ks * 32 + rq * 8 + i;
      const float* Wrow = (k < E_DIM) ? (W_ih + k * G_DIM) : (W_hh + (k - E_DIM) * G_DIM);
#pragma unroll
      for (int gt = 0; gt < 4; ++gt)
        B[gt][ks][i] = (short)f2bf(Wrow[gt * 128 + u]);
    }

  // log2e-scaled negative biases (fold exp scale into one fma per gate)
  const float nbi = -K1 * (b_ih[u]       + b_hh[u]);
  const float nbf = -K1 * (b_ih[128 + u] + b_hh[128 + u]);
  const float nbg = -K2 * (b_ih[256 + u] + b_hh[256 + u]);
  const float nbo = -K1 * (b_ih[384 + u] + b_hh[384 + u]);

  __syncthreads();  // We/be/Wp visible

  // ---- e for first active obs step ----
  if (s_min <= L_OBS - 2) {
    const f32x2 rr = *(const f32x2*)(obs_rel + (wg0 + grow) * (L_OBS * 2) + (s_min + 1) * 2);
    const int j = c2 * 2;
    const float e0 = fmaf(rr.x, We_lds[0][j],     fmaf(rr.y, We_lds[1][j],     be_lds[j]));
    const float e1 = fmaf(rr.x, We_lds[0][j + 1], fmaf(rr.y, We_lds[1][j + 1], be_lds[j + 1]));
    const unsigned int pk = (unsigned int)f2bf(fmaxf(e0, 0.f)) | ((unsigned int)f2bf(fmaxf(e1, 0.f)) << 16);
    *(unsigned int*)&A_lds[0][grow][j] = pk;
  }

  // ---- pos init + img_proj (32 lanes per row, float4 coalesced) ----
  float pos0 = obs_pos[(wg0 + grow) * (L_OBS * 2) + (L_OBS - 1) * 2];
  float pos1 = obs_pos[(wg0 + grow) * (L_OBS * 2) + (L_OBS - 1) * 2 + 1];
  float ip0 = 0.f, ip1 = 0.f;
  {
    const float* irow = img + (long)(wg0 + grow) * C_DIM;
#pragma unroll 4
    for (int i = 0; i < 16; ++i) {
      const int k0 = i * 128 + c2 * 4;
      const f32x4 v  = *(const f32x4*)(irow + k0);
      const f32x4 wa = *(const f32x4*)(W_pred + (H_DIM + k0) * 2);
      const f32x4 wb = *(const f32x4*)(W_pred + (H_DIM + k0) * 2 + 4);
      ip0 = fmaf(v.x, wa.x, fmaf(v.y, wa.z, fmaf(v.z, wb.x, fmaf(v.w, wb.z, ip0))));
      ip1 = fmaf(v.x, wa.y, fmaf(v.y, wa.w, fmaf(v.z, wb.y, fmaf(v.w, wb.w, ip1))));
    }
#pragma unroll
    for (int m = 16; m >= 1; m >>= 1) { ip0 += __shfl_xor(ip0, m); ip1 += __shfl_xor(ip1, m); }
    ip0 += b_pred[0]; ip1 += b_pred[1];
  }
  __syncthreads();  // A_lds[0] ready

  int cur = 0;

  auto lstm_step = [&](int cur_, int nxt_, int s_, bool domask) {
    f32x4 acc[4];
#pragma unroll
    for (int gt = 0; gt < 4; ++gt) { acc[gt].x = 0.f; acc[gt].y = 0.f; acc[gt].z = 0.f; acc[gt].w = 0.f; }
#pragma unroll
    for (int ks = 0; ks < 6; ++ks) {
      const bf16x8 a = *(const bf16x8*)&A_lds[cur_][u15][ks * 32 + rq * 8];
#pragma unroll
      for (int gt = 0; gt < 4; ++gt)
        acc[gt] = __builtin_amdgcn_mfma_f32_16x16x32_bf16(a, B[gt][ks], acc[gt], 0, 0, 0);
    }
#pragma unroll
    for (int q = 0; q < 4; ++q) {
      const float si = rcpn(1.f + ex2(fmaf(acc[0][q], -K1, nbi)));
      const float sf = rcpn(1.f + ex2(fmaf(acc[1][q], -K1, nbf)));
      const float tg = fmaf(2.f, rcpn(1.f + ex2(fmaf(acc[2][q], -K2, nbg))), -1.f);
      const float so = rcpn(1.f + ex2(fmaf(acc[3][q], -K1, nbo)));
      const float cn = fmaf(sf, cs[q], si * tg);
      const float tc = fmaf(2.f, rcpn(1.f + ex2(-K2 * cn)), -1.f);
      const float hn = so * tc;
      bool act = true;
      if (domask) act = s_ >= ((sact >> (8 * q)) & 255);
      if (act) { cs[q] = cn; hb[q] = f2bf(hn); }
      A_lds[nxt_][rq * 4 + q][64 + u] = hb[q];
    }
  };

  // ================= obs phase (first s_min steps provably no-ops) =================
#pragma unroll 1
  for (int s = s_min; s < L_OBS - 1; ++s) {
    const int nxt = cur ^ 1;
    f32x2 rrN;
    const bool havN = (s + 2) <= (L_OBS - 1);
    if (havN) rrN = *(const f32x2*)(obs_rel + (wg0 + grow) * (L_OBS * 2) + (s + 2) * 2);
    lstm_step(cur, nxt, s, true);
    if (havN) {
      const int j = c2 * 2;
      const float e0 = fmaf(rrN.x, We_lds[0][j],     fmaf(rrN.y, We_lds[1][j],     be_lds[j]));
      const float e1 = fmaf(rrN.x, We_lds[0][j + 1], fmaf(rrN.y, We_lds[1][j + 1], be_lds[j + 1]));
      const unsigned int pk = (unsigned int)f2bf(fmaxf(e0, 0.f)) | ((unsigned int)f2bf(fmaxf(e1, 0.f)) << 16);
      *(unsigned int*)&A_lds[nxt][grow][j] = pk;
    }
    cur = nxt;
    __syncthreads();
  }

  // ================= pred phase: 30 steps =================
#pragma unroll 1
  for (int p = 0; p < P_PRED; ++p) {
    // rel = h @ Wp_h + img_proj  (32 lanes per row, 4 units each)
    const s16x4 hv = *(const s16x4*)&A_lds[cur][grow][64 + c2 * 4];
    float s0 = 0.f, s1 = 0.f;
#pragma unroll
    for (int i = 0; i < 4; ++i) {
      const float hf = bf2f((unsigned short)hv[i]);
      s0 = fmaf(hf, Wp_lds[c2 * 4 + i][0], s0);
      s1 = fmaf(hf, Wp_lds[c2 * 4 + i][1], s1);
    }
#pragma unroll
    for (int m = 16; m >= 1; m >>= 1) { s0 += __shfl_xor(s0, m); s1 += __shfl_xor(s1, m); }
    const float rel0 = s0 + ip0, rel1 = s1 + ip1;
    pos0 += rel0; pos1 += rel1;
    if (c2 == 0) {
      float2 o; o.x = pos0; o.y = pos1;
      *(float2*)&out[((long)(wg0 + grow) * P_PRED + p) * 2] = o;
    }
    if (p == P_PRED - 1) break;

    // e = relu(rel @ W_embed + b_embed) into current buffer (cols 0..63; disjoint from h reads)
    {
      const int j = c2 * 2;
      const float e0 = fmaf(rel0, We_lds[0][j],     fmaf(rel1, We_lds[1][j],     be_lds[j]));
      const float e1 = fmaf(rel0, We_lds[0][j + 1], fmaf(rel1, We_lds[1][j + 1], be_lds[j + 1]));
      const unsigned int pk = (unsigned int)f2bf(fmaxf(e0, 0.f)) | ((unsigned int)f2bf(fmaxf(e1, 0.f)) << 16);
      *(unsigned int*)&A_lds[cur][grow][j] = pk;
    }
    __syncthreads();

    const int nxt = cur ^ 1;
    lstm_step(cur, nxt, 0, false);
    cur = nxt;
    __syncthreads();
  }
}

extern "C" void kernel_launch(void* const* d_in, const int* in_sizes, int n_in,
                              void* d_out, int out_size, void* d_ws, size_t ws_size,
                              hipStream_t stream) {
  (void)in_sizes; (void)n_in; (void)out_size; (void)d_ws; (void)ws_size;
  lstm_traj<<<dim3(N_TOT / M_ROWS), dim3(NTH), 0, stream>>>(
      (const float*)d_in[0],  // img_embedding
      (const float*)d_in[1],  // obs_pos
      (const float*)d_in[2],  // obs_pos_rel
      (const int*)  d_in[3],  // obs_hist_size
      (const float*)d_in[4],  // h0
      (const float*)d_in[5],  // W_embed
      (const float*)d_in[6],  // b_embed
      (const float*)d_in[7],  // W_ih
      (const float*)d_in[8],  // W_hh
      (const float*)d_in[9],  // b_ih
      (const float*)d_in[10], // b_hh
      (const float*)d_in[11], // W_pred
      (const float*)d_in[12], // b_pred
      (float*)d_out);
}

// Round 3
// 128.784 us; speedup vs baseline: 2.1972x; 2.1972x over previous
//
#include <hip/hip_runtime.h>

typedef float f32x4 __attribute__((ext_vector_type(4)));
typedef float f32x2 __attribute__((ext_vector_type(2)));
typedef short bf16x8 __attribute__((ext_vector_type(8)));
typedef short short4v __attribute__((ext_vector_type(4)));

#define N_TOT 8192
#define L_OBS 20
#define P_PRED 30
#define E_DIM 64
#define H_DIM 128
#define C_DIM 2048
#define G_DIM 512
#define M_ROWS 32
#define NTH 512
#define A_PAD 200   // bf16 elems per A row (400 B rows, 16B aligned)

#define K1 1.442695041f
#define K2 2.885390082f

static __device__ __forceinline__ unsigned short f2bf(float f) {
  union { float f; unsigned int u; } v; v.f = f;
  unsigned int u = v.u;
  return (unsigned short)((u + 0x7FFFu + ((u >> 16) & 1u)) >> 16);
}
static __device__ __forceinline__ float bf2f(unsigned short b) {
  union { unsigned int u; float f; } v; v.u = ((unsigned int)b) << 16;
  return v.f;
}
// native transcendentals: avoid IEEE f32 div sequence without -ffast-math
static __device__ __forceinline__ float ex2(float x)  { float r; asm("v_exp_f32 %0, %1" : "=v"(r) : "v"(x)); return r; }
static __device__ __forceinline__ float rcpn(float x) { float r; asm("v_rcp_f32 %0, %1" : "=v"(r) : "v"(x)); return r; }

__global__ __launch_bounds__(NTH, 2)
void lstm_traj(const float* __restrict__ img,      // [N][C]
               const float* __restrict__ obs_pos,  // [N][L][2]
               const float* __restrict__ obs_rel,  // [N][L][2]
               const int*   __restrict__ hist,     // [N]
               const float* __restrict__ h0,       // [H]
               const float* __restrict__ W_embed,  // [2][E]
               const float* __restrict__ b_embed,  // [E]
               const float* __restrict__ W_ih,     // [E][4H]
               const float* __restrict__ W_hh,     // [H][4H]
               const float* __restrict__ b_ih,     // [4H]
               const float* __restrict__ b_hh,     // [4H]
               const float* __restrict__ W_pred,   // [H+C][2]
               const float* __restrict__ b_pred,   // [2]
               float* __restrict__ out)            // [N][P][2]
{
  __shared__ unsigned short A_lds[2][M_ROWS][A_PAD]; // [e(64) | h(128) | pad]
  __shared__ float We_lds[2][E_DIM];
  __shared__ float be_lds[E_DIM];
  __shared__ float Wp_lds[H_DIM][2];

  const int t    = threadIdx.x;
  const int w    = t >> 6;        // wave 0..7
  const int l    = t & 63;
  const int u15  = l & 15;        // MFMA A-row / D-col index
  const int rq   = l >> 4;        // MFMA k-group / row-quad
  const int u    = w * 16 + u15;  // owned hidden unit 0..127
  const int wg0  = blockIdx.x * M_ROWS;
  const int grow = t >> 4;        // 0..31: row for e/rel/img work
  const int gj   = t & 15;        // 0..15: slot within row group

  // ---- stage small weights to LDS ----
  if (t < 128) We_lds[t >> 6][t & 63] = W_embed[t];
  if (t < 64)  be_lds[t] = b_embed[t];
  if (t >= 128 && t < 384) ((float*)Wp_lds)[t - 128] = W_pred[t - 128];
  __syncthreads();

  // ---- B fragments (weights) in registers: 24 frags = 96 VGPR ----
  bf16x8 B[4][6];
#pragma unroll
  for (int ks = 0; ks < 6; ++ks)
#pragma unroll
    for (int i = 0; i < 8; ++i) {
      const int k = ks * 32 + rq * 8 + i;
      const float* Wrow = (k < E_DIM) ? (W_ih + k * G_DIM) : (W_hh + (k - E_DIM) * G_DIM);
#pragma unroll
      for (int gt = 0; gt < 4; ++gt)
        B[gt][ks][i] = (short)f2bf(Wrow[gt * 128 + u]);
    }

  // log2e-scaled negative biases (fold the exp2 scale into one fma per gate)
  const float nbi = -K1 * (b_ih[u]       + b_hh[u]);
  const float nbf = -K1 * (b_ih[128 + u] + b_hh[128 + u]);
  const float nbg = -K2 * (b_ih[256 + u] + b_hh[256 + u]);
  const float nbo = -K1 * (b_ih[384 + u] + b_hh[384 + u]);

  // ---- per-lane recurrent state: rows rt*16 + rq*4 + q, unit u ----
  const float h0u = h0[u];
  const unsigned short h0b = f2bf(h0u);
  unsigned short hb[2][4];
  float cs[2][4];
  int sact[2];  // per-q packed first-active-step (20 - hist), 8 bits each
#pragma unroll
  for (int rt = 0; rt < 2; ++rt) {
    sact[rt] = 0;
#pragma unroll
    for (int q = 0; q < 4; ++q) {
      const int row = rt * 16 + rq * 4 + q;
      hb[rt][q] = h0b; cs[rt][q] = h0u;
      sact[rt] |= ((20 - hist[wg0 + row]) & 255) << (8 * q);
      A_lds[0][row][64 + u] = h0b;
    }
  }

  // ---- e for obs step 1 (uses obs_rel[:,2,:]) ----
  {
    const f32x2 rr = *(const f32x2*)(obs_rel + (wg0 + grow) * (L_OBS * 2) + 2 * 2);
    short4v ep;
#pragma unroll
    for (int i = 0; i < 4; ++i) {
      const int j = gj * 4 + i;
      float e = fmaf(rr.x, We_lds[0][j], fmaf(rr.y, We_lds[1][j], be_lds[j]));
      ep[i] = (short)f2bf(fmaxf(e, 0.0f));
    }
    *(short4v*)&A_lds[0][grow][gj * 4] = ep;
  }

  // ---- pos init + img_proj (16 lanes per row, coalesced float4) ----
  float pos0 = obs_pos[(wg0 + grow) * (L_OBS * 2) + (L_OBS - 1) * 2];
  float pos1 = obs_pos[(wg0 + grow) * (L_OBS * 2) + (L_OBS - 1) * 2 + 1];
  float ip0 = 0.f, ip1 = 0.f;
  {
    const float* irow = img + (long)(wg0 + grow) * C_DIM;
#pragma unroll 4
    for (int i = 0; i < 32; ++i) {
      const int k0 = i * 64 + gj * 4;
      const f32x4 v  = *(const f32x4*)(irow + k0);
      const f32x4 wa = *(const f32x4*)(W_pred + (H_DIM + k0) * 2);
      const f32x4 wb = *(const f32x4*)(W_pred + (H_DIM + k0) * 2 + 4);
      ip0 = fmaf(v.x, wa.x, fmaf(v.y, wa.z, fmaf(v.z, wb.x, fmaf(v.w, wb.z, ip0))));
      ip1 = fmaf(v.x, wa.y, fmaf(v.y, wa.w, fmaf(v.z, wb.y, fmaf(v.w, wb.w, ip1))));
    }
#pragma unroll
    for (int m = 8; m >= 1; m >>= 1) { ip0 += __shfl_xor(ip0, m); ip1 += __shfl_xor(ip1, m); }
    ip0 += b_pred[0]; ip1 += b_pred[1];
  }
  __syncthreads();

  int cur = 0;

  auto lstm_step = [&](int cur_, int nxt_, int s_, bool domask) {
    f32x4 acc[2][4];
#pragma unroll
    for (int rt = 0; rt < 2; ++rt) {
#pragma unroll
      for (int gt = 0; gt < 4; ++gt) { acc[rt][gt].x = 0.f; acc[rt][gt].y = 0.f; acc[rt][gt].z = 0.f; acc[rt][gt].w = 0.f; }
#pragma unroll
      for (int ks = 0; ks < 6; ++ks) {
        const bf16x8 a = *(const bf16x8*)&A_lds[cur_][rt * 16 + u15][ks * 32 + rq * 8];
#pragma unroll
        for (int gt = 0; gt < 4; ++gt)
          acc[rt][gt] = __builtin_amdgcn_mfma_f32_16x16x32_bf16(a, B[gt][ks], acc[rt][gt], 0, 0, 0);
      }
    }
#pragma unroll
    for (int rt = 0; rt < 2; ++rt)
#pragma unroll
      for (int q = 0; q < 4; ++q) {
        const float si = rcpn(1.f + ex2(fmaf(acc[rt][0][q], -K1, nbi)));
        const float sf = rcpn(1.f + ex2(fmaf(acc[rt][1][q], -K1, nbf)));
        const float tg = fmaf(2.f, rcpn(1.f + ex2(fmaf(acc[rt][2][q], -K2, nbg))), -1.f);
        const float so = rcpn(1.f + ex2(fmaf(acc[rt][3][q], -K1, nbo)));
        const float cn = fmaf(sf, cs[rt][q], si * tg);
        const float tc = fmaf(2.f, rcpn(1.f + ex2(-K2 * cn)), -1.f);
        const float hn = so * tc;
        bool act = true;
        if (domask) act = s_ >= ((sact[rt] >> (8 * q)) & 255);
        if (act) { cs[rt][q] = cn; hb[rt][q] = f2bf(hn); }
        A_lds[nxt_][rt * 16 + rq * 4 + q][64 + u] = hb[rt][q];
      }
  };

  // ================= obs phase: steps 1..18 (step 0 provably inactive) =================
#pragma unroll 1
  for (int s = 1; s < L_OBS - 1; ++s) {
    const int nxt = cur ^ 1;
    f32x2 rrN;
    const bool havN = (s + 2) <= (L_OBS - 1);
    if (havN) rrN = *(const f32x2*)(obs_rel + (wg0 + grow) * (L_OBS * 2) + (s + 2) * 2);
    lstm_step(cur, nxt, s, true);
    if (havN) {
      short4v ep;
#pragma unroll
      for (int i = 0; i < 4; ++i) {
        const int j = gj * 4 + i;
        float e = fmaf(rrN.x, We_lds[0][j], fmaf(rrN.y, We_lds[1][j], be_lds[j]));
        ep[i] = (short)f2bf(fmaxf(e, 0.0f));
      }
      *(short4v*)&A_lds[nxt][grow][gj * 4] = ep;
    }
    cur = nxt;
    __syncthreads();
  }

  // ================= pred phase: 30 steps =================
#pragma unroll 1
  for (int p = 0; p < P_PRED; ++p) {
    // rel = h @ Wp_h + img_proj  (16 lanes per row, 8 units each)
    const bf16x8 hv = *(const bf16x8*)&A_lds[cur][grow][64 + gj * 8];
    float s0 = 0.f, s1 = 0.f;
#pragma unroll
    for (int i = 0; i < 8; ++i) {
      const float hf = bf2f((unsigned short)hv[i]);
      s0 = fmaf(hf, Wp_lds[gj * 8 + i][0], s0);
      s1 = fmaf(hf, Wp_lds[gj * 8 + i][1], s1);
    }
#pragma unroll
    for (int m = 8; m >= 1; m >>= 1) { s0 += __shfl_xor(s0, m); s1 += __shfl_xor(s1, m); }
    const float rel0 = s0 + ip0, rel1 = s1 + ip1;
    pos0 += rel0; pos1 += rel1;
    if (gj == 0) {
      float2 o; o.x = pos0; o.y = pos1;
      *(float2*)&out[((long)(wg0 + grow) * P_PRED + p) * 2] = o;
    }
    if (p == P_PRED - 1) break;

    // e = relu(rel @ W_embed + b_embed) into current buffer (cols 0..63, disjoint from h)
    {
      short4v ep;
#pragma unroll
      for (int i = 0; i < 4; ++i) {
        const int j = gj * 4 + i;
        float e = fmaf(rel0, We_lds[0][j], fmaf(rel1, We_lds[1][j], be_lds[j]));
        ep[i] = (short)f2bf(fmaxf(e, 0.0f));
      }
      *(short4v*)&A_lds[cur][grow][gj * 4] = ep;
    }
    __syncthreads();

    const int nxt = cur ^ 1;
    lstm_step(cur, nxt, 0, false);
    cur = nxt;
    __syncthreads();
  }
}

extern "C" void kernel_launch(void* const* d_in, const int* in_sizes, int n_in,
                              void* d_out, int out_size, void* d_ws, size_t ws_size,
                              hipStream_t stream) {
  (void)in_sizes; (void)n_in; (void)out_size; (void)d_ws; (void)ws_size;
  lstm_traj<<<dim3(N_TOT / M_ROWS), dim3(NTH), 0, stream>>>(
      (const float*)d_in[0],  // img_embedding
      (const float*)d_in[1],  // obs_pos
      (const float*)d_in[2],  // obs_pos_rel
      (const int*)  d_in[3],  // obs_hist_size
      (const float*)d_in[4],  // h0
      (const float*)d_in[5],  // W_embed
      (const float*)d_in[6],  // b_embed
      (const float*)d_in[7],  // W_ih
      (const float*)d_in[8],  // W_hh
      (const float*)d_in[9],  // b_ih
      (const float*)d_in[10], // b_hh
      (const float*)d_in[11], // W_pred
      (const float*)d_in[12], // b_pred
      (float*)d_out);
}

// Round 4
// 125.038 us; speedup vs baseline: 2.2630x; 1.0300x over previous
//
#include <hip/hip_runtime.h>

typedef float f32x4 __attribute__((ext_vector_type(4)));
typedef float f32x2 __attribute__((ext_vector_type(2)));
typedef short bf16x8 __attribute__((ext_vector_type(8)));

#define N_TOT 8192
#define L_OBS 20
#define P_PRED 30
#define E_DIM 64
#define H_DIM 128
#define C_DIM 2048
#define G_DIM 512
#define M_ROWS 32
#define NTH 512
#define A_PAD 200   // bf16 elems per A row (400 B rows, 16B aligned)

#define K1 1.442695041f
#define K2 2.885390082f

static __device__ __forceinline__ unsigned short f2bf(float f) {
  union { float f; unsigned int u; } v; v.f = f;
  unsigned int u = v.u;
  return (unsigned short)((u + 0x7FFFu + ((u >> 16) & 1u)) >> 16);
}
static __device__ __forceinline__ float bf2f(unsigned short b) {
  union { unsigned int u; float f; } v; v.u = ((unsigned int)b) << 16;
  return v.f;
}
// native transcendentals: avoid IEEE f32 div sequence without -ffast-math
static __device__ __forceinline__ float ex2(float x)  { float r; asm("v_exp_f32 %0, %1" : "=v"(r) : "v"(x)); return r; }
static __device__ __forceinline__ float rcpn(float x) { float r; asm("v_rcp_f32 %0, %1" : "=v"(r) : "v"(x)); return r; }
// HW round-to-nearest-even f32 pair -> packed bf16
static __device__ __forceinline__ unsigned int cvtpk(float lo, float hi) {
  unsigned int r; asm("v_cvt_pk_bf16_f32 %0, %1, %2" : "=v"(r) : "v"(lo), "v"(hi)); return r;
}

__global__ __launch_bounds__(NTH, 2)
void lstm_traj(const float* __restrict__ img,      // [N][C]
               const float* __restrict__ obs_pos,  // [N][L][2]
               const float* __restrict__ obs_rel,  // [N][L][2]
               const int*   __restrict__ hist,     // [N]
               const float* __restrict__ h0,       // [H]
               const float* __restrict__ W_embed,  // [2][E]
               const float* __restrict__ b_embed,  // [E]
               const float* __restrict__ W_ih,     // [E][4H]
               const float* __restrict__ W_hh,     // [H][4H]
               const float* __restrict__ b_ih,     // [4H]
               const float* __restrict__ b_hh,     // [4H]
               const float* __restrict__ W_pred,   // [H+C][2]
               const float* __restrict__ b_pred,   // [2]
               float* __restrict__ out)            // [N][P][2]
{
  __shared__ unsigned short A_lds[2][M_ROWS][A_PAD]; // [e(64) | h(128) | pad]
  __shared__ float We_lds[2][E_DIM];
  __shared__ float be_lds[E_DIM];
  __shared__ float Wp_lds[H_DIM][2];

  const int t    = threadIdx.x;
  const int w    = t >> 6;        // wave 0..7
  const int l    = t & 63;
  const int u15  = l & 15;        // MFMA A-row / D-col index
  const int rq   = l >> 4;        // MFMA k-group / row-quad
  const int u    = w * 16 + u15;  // owned hidden unit 0..127
  const int wg0  = blockIdx.x * M_ROWS;
  const int grow = t >> 4;        // 0..31: row for e/rel/img work
  const int gj   = t & 15;        // 0..15: slot within row group

  const float* relrow = obs_rel + (wg0 + grow) * (L_OBS * 2);

  // ---- stage small weights to LDS ----
  if (t < 128) We_lds[t >> 6][t & 63] = W_embed[t];
  if (t < 64)  be_lds[t] = b_embed[t];
  if (t >= 128 && t < 384) ((float*)Wp_lds)[t - 128] = W_pred[t - 128];
  __syncthreads();

  // ---- B fragments (weights) in registers: 24 frags = 96 VGPR ----
  bf16x8 B[4][6];
#pragma unroll
  for (int ks = 0; ks < 6; ++ks)
#pragma unroll
    for (int i = 0; i < 8; ++i) {
      const int k = ks * 32 + rq * 8 + i;
      const float* Wrow = (k < E_DIM) ? (W_ih + k * G_DIM) : (W_hh + (k - E_DIM) * G_DIM);
#pragma unroll
      for (int gt = 0; gt < 4; ++gt)
        B[gt][ks][i] = (short)f2bf(Wrow[gt * 128 + u]);
    }

  // log2e-scaled negative biases (fold the exp2 scale into one fma per gate)
  const float nbi = -K1 * (b_ih[u]       + b_hh[u]);
  const float nbf = -K1 * (b_ih[128 + u] + b_hh[128 + u]);
  const float nbg = -K2 * (b_ih[256 + u] + b_hh[256 + u]);
  const float nbo = -K1 * (b_ih[384 + u] + b_hh[384 + u]);

  // ---- per-lane recurrent state: rows rt*16 + rq*4 + q, unit u ----
  const float h0u = h0[u];
  const unsigned short h0b = f2bf(h0u);
  float hf[2][4];   // h as f32 (converted to bf16 at each LDS write)
  float cs[2][4];
  int sact[2];      // per-q packed first-active-step (20 - hist), 8 bits each
#pragma unroll
  for (int rt = 0; rt < 2; ++rt) {
    sact[rt] = 0;
#pragma unroll
    for (int q = 0; q < 4; ++q) {
      const int row = rt * 16 + rq * 4 + q;
      hf[rt][q] = h0u; cs[rt][q] = h0u;
      sact[rt] |= ((20 - hist[wg0 + row]) & 255) << (8 * q);
      A_lds[0][row][64 + u] = h0b;
    }
  }

  // ---- e for obs step 1 (uses obs_rel[:,2,:]) ----
  {
    const f32x2 rr = *(const f32x2*)(relrow + 2 * 2);
    const int j = gj * 4;
    const float e0 = fmaxf(fmaf(rr.x, We_lds[0][j],     fmaf(rr.y, We_lds[1][j],     be_lds[j])),     0.f);
    const float e1 = fmaxf(fmaf(rr.x, We_lds[0][j + 1], fmaf(rr.y, We_lds[1][j + 1], be_lds[j + 1])), 0.f);
    const float e2 = fmaxf(fmaf(rr.x, We_lds[0][j + 2], fmaf(rr.y, We_lds[1][j + 2], be_lds[j + 2])), 0.f);
    const float e3 = fmaxf(fmaf(rr.x, We_lds[0][j + 3], fmaf(rr.y, We_lds[1][j + 3], be_lds[j + 3])), 0.f);
    uint2 pk; pk.x = cvtpk(e0, e1); pk.y = cvtpk(e2, e3);
    *(uint2*)&A_lds[0][grow][j] = pk;
  }

  // ---- pos init + img_proj (16 lanes per row, coalesced float4) ----
  float pos0 = obs_pos[(wg0 + grow) * (L_OBS * 2) + (L_OBS - 1) * 2];
  float pos1 = obs_pos[(wg0 + grow) * (L_OBS * 2) + (L_OBS - 1) * 2 + 1];
  float ip0 = 0.f, ip1 = 0.f;
  {
    const float* irow = img + (long)(wg0 + grow) * C_DIM;
#pragma unroll 4
    for (int i = 0; i < 32; ++i) {
      const int k0 = i * 64 + gj * 4;
      const f32x4 v  = *(const f32x4*)(irow + k0);
      const f32x4 wa = *(const f32x4*)(W_pred + (H_DIM + k0) * 2);
      const f32x4 wb = *(const f32x4*)(W_pred + (H_DIM + k0) * 2 + 4);
      ip0 = fmaf(v.x, wa.x, fmaf(v.y, wa.z, fmaf(v.z, wb.x, fmaf(v.w, wb.z, ip0))));
      ip1 = fmaf(v.x, wa.y, fmaf(v.y, wa.w, fmaf(v.z, wb.y, fmaf(v.w, wb.w, ip1))));
    }
#pragma unroll
    for (int m = 8; m >= 1; m >>= 1) { ip0 += __shfl_xor(ip0, m); ip1 += __shfl_xor(ip1, m); }
    ip0 += b_pred[0]; ip1 += b_pred[1];
  }
  __syncthreads();

  int cur = 0;

  // gate nonlinearity + h-write: 5 ex2 + 3 rcp per output
  auto gates_and_h = [&](f32x4 (&acc)[2][4], int nxt_, int s_, bool domask) {
#pragma unroll
    for (int rt = 0; rt < 2; ++rt) {
#pragma unroll
      for (int q = 0; q < 4; ++q) {
        const float A_ = ex2(fmaf(acc[rt][0][q], -K1, nbi));
        const float F_ = ex2(fmaf(acc[rt][1][q], -K1, nbf));
        const float B_ = ex2(fmaf(acc[rt][2][q], -K2, nbg));
        const float C_ = ex2(fmaf(acc[rt][3][q], -K1, nbo));
        const float P2 = 1.f + B_;
        const float PB = (1.f + A_) * P2;
        const float Q  = 1.f + F_;
        // cn = c/(1+F) + (1-B)/((1+A)(1+B))
        const float cn = fmaf(cs[rt][q], PB, (2.f - P2) * Q) * rcpn(PB * Q);
        const float D_ = ex2(-K2 * cn);
        const float tc = fmaf(2.f, rcpn(1.f + D_), -1.f);  // tanh(cn), inf-safe
        const float hn = tc * rcpn(1.f + C_);              // * sigmoid(o)
        bool act = true;
        if (domask) act = s_ >= ((sact[rt] >> (8 * q)) & 255);
        if (act) { cs[rt][q] = cn; hf[rt][q] = hn; }
      }
      const unsigned int p01 = cvtpk(hf[rt][0], hf[rt][1]);
      const unsigned int p23 = cvtpk(hf[rt][2], hf[rt][3]);
      const int rowb = rt * 16 + rq * 4;
      A_lds[nxt_][rowb + 0][64 + u] = (unsigned short)p01;
      A_lds[nxt_][rowb + 1][64 + u] = (unsigned short)(p01 >> 16);
      A_lds[nxt_][rowb + 2][64 + u] = (unsigned short)p23;
      A_lds[nxt_][rowb + 3][64 + u] = (unsigned short)(p23 >> 16);
    }
  };

  // ================= obs phase: steps 1..18 (step 0 provably inactive) =================
#pragma unroll 1
  for (int s = 1; s < L_OBS - 1; ++s) {
    const int nxt = cur ^ 1;
    const int sN = (s + 2 <= L_OBS - 1) ? (s + 2) : (L_OBS - 1);  // branchless prefetch idx
    const f32x2 rrN = *(const f32x2*)(relrow + sN * 2);

    f32x4 acc[2][4];
#pragma unroll
    for (int rt = 0; rt < 2; ++rt)
#pragma unroll
      for (int gt = 0; gt < 4; ++gt) { acc[rt][gt].x = 0.f; acc[rt][gt].y = 0.f; acc[rt][gt].z = 0.f; acc[rt][gt].w = 0.f; }
#pragma unroll
    for (int ks = 0; ks < 6; ++ks)
#pragma unroll
      for (int rt = 0; rt < 2; ++rt) {
        const bf16x8 a = *(const bf16x8*)&A_lds[cur][rt * 16 + u15][ks * 32 + rq * 8];
#pragma unroll
        for (int gt = 0; gt < 4; ++gt)
          acc[rt][gt] = __builtin_amdgcn_mfma_f32_16x16x32_bf16(a, B[gt][ks], acc[rt][gt], 0, 0, 0);
      }

    // next-step e into A[nxt] (overlaps MFMA latency; garbage on last iter, overwritten in pred)
    {
      const int j = gj * 4;
      const float e0 = fmaxf(fmaf(rrN.x, We_lds[0][j],     fmaf(rrN.y, We_lds[1][j],     be_lds[j])),     0.f);
      const float e1 = fmaxf(fmaf(rrN.x, We_lds[0][j + 1], fmaf(rrN.y, We_lds[1][j + 1], be_lds[j + 1])), 0.f);
      const float e2 = fmaxf(fmaf(rrN.x, We_lds[0][j + 2], fmaf(rrN.y, We_lds[1][j + 2], be_lds[j + 2])), 0.f);
      const float e3 = fmaxf(fmaf(rrN.x, We_lds[0][j + 3], fmaf(rrN.y, We_lds[1][j + 3], be_lds[j + 3])), 0.f);
      uint2 pk; pk.x = cvtpk(e0, e1); pk.y = cvtpk(e2, e3);
      *(uint2*)&A_lds[nxt][grow][j] = pk;
    }

    gates_and_h(acc, nxt, s, true);
    cur = nxt;
    __syncthreads();
  }

  // ================= pred phase: 30 steps =================
#pragma unroll 1
  for (int p = 0; p < P_PRED; ++p) {
    f32x4 acc[2][4];
    const bool last = (p == P_PRED - 1);
    if (!last) {
      // h-part MFMAs (ks 2..5) — h of A[cur] is valid now; overlaps rel/e phase
#pragma unroll
      for (int rt = 0; rt < 2; ++rt)
#pragma unroll
        for (int gt = 0; gt < 4; ++gt) { acc[rt][gt].x = 0.f; acc[rt][gt].y = 0.f; acc[rt][gt].z = 0.f; acc[rt][gt].w = 0.f; }
#pragma unroll
      for (int ks = 2; ks < 6; ++ks)
#pragma unroll
        for (int rt = 0; rt < 2; ++rt) {
          const bf16x8 a = *(const bf16x8*)&A_lds[cur][rt * 16 + u15][ks * 32 + rq * 8];
#pragma unroll
          for (int gt = 0; gt < 4; ++gt)
            acc[rt][gt] = __builtin_amdgcn_mfma_f32_16x16x32_bf16(a, B[gt][ks], acc[rt][gt], 0, 0, 0);
        }
    }

    // rel = h @ Wp_h + img_proj  (16 lanes per row, 8 units each)
    const bf16x8 hv = *(const bf16x8*)&A_lds[cur][grow][64 + gj * 8];
    float s0 = 0.f, s1 = 0.f;
#pragma unroll
    for (int i = 0; i < 8; ++i) {
      const float hfv = bf2f((unsigned short)hv[i]);
      s0 = fmaf(hfv, Wp_lds[gj * 8 + i][0], s0);
      s1 = fmaf(hfv, Wp_lds[gj * 8 + i][1], s1);
    }
#pragma unroll
    for (int m = 8; m >= 1; m >>= 1) { s0 += __shfl_xor(s0, m); s1 += __shfl_xor(s1, m); }
    const float rel0 = s0 + ip0, rel1 = s1 + ip1;
    pos0 += rel0; pos1 += rel1;
    if (gj == 0) {
      float2 o; o.x = pos0; o.y = pos1;
      *(float2*)&out[((long)(wg0 + grow) * P_PRED + p) * 2] = o;
    }
    if (last) break;

    // e = relu(rel @ W_embed + b_embed) into A[cur] cols 0..63
    {
      const int j = gj * 4;
      const float e0 = fmaxf(fmaf(rel0, We_lds[0][j],     fmaf(rel1, We_lds[1][j],     be_lds[j])),     0.f);
      const float e1 = fmaxf(fmaf(rel0, We_lds[0][j + 1], fmaf(rel1, We_lds[1][j + 1], be_lds[j + 1])), 0.f);
      const float e2 = fmaxf(fmaf(rel0, We_lds[0][j + 2], fmaf(rel1, We_lds[1][j + 2], be_lds[j + 2])), 0.f);
      const float e3 = fmaxf(fmaf(rel0, We_lds[0][j + 3], fmaf(rel1, We_lds[1][j + 3], be_lds[j + 3])), 0.f);
      uint2 pk; pk.x = cvtpk(e0, e1); pk.y = cvtpk(e2, e3);
      *(uint2*)&A_lds[cur][grow][j] = pk;
    }
    __syncthreads();  // barrier B: e visible

    // e-part MFMAs (ks 0..1)
#pragma unroll
    for (int ks = 0; ks < 2; ++ks)
#pragma unroll
      for (int rt = 0; rt < 2; ++rt) {
        const bf16x8 a = *(const bf16x8*)&A_lds[cur][rt * 16 + u15][ks * 32 + rq * 8];
#pragma unroll
        for (int gt = 0; gt < 4; ++gt)
          acc[rt][gt] = __builtin_amdgcn_mfma_f32_16x16x32_bf16(a, B[gt][ks], acc[rt][gt], 0, 0, 0);
      }

    const int nxt = cur ^ 1;
    gates_and_h(acc, nxt, 0, false);
    cur = nxt;
    __syncthreads();  // barrier A: h visible
  }
}

extern "C" void kernel_launch(void* const* d_in, const int* in_sizes, int n_in,
                              void* d_out, int out_size, void* d_ws, size_t ws_size,
                              hipStream_t stream) {
  (void)in_sizes; (void)n_in; (void)out_size; (void)d_ws; (void)ws_size;
  lstm_traj<<<dim3(N_TOT / M_ROWS), dim3(NTH), 0, stream>>>(
      (const float*)d_in[0],  // img_embedding
      (const float*)d_in[1],  // obs_pos
      (const float*)d_in[2],  // obs_pos_rel
      (const int*)  d_in[3],  // obs_hist_size
      (const float*)d_in[4],  // h0
      (const float*)d_in[5],  // W_embed
      (const float*)d_in[6],  // b_embed
      (const float*)d_in[7],  // W_ih
      (const float*)d_in[8],  // W_hh
      (const float*)d_in[9],  // b_ih
      (const float*)d_in[10], // b_hh
      (const float*)d_in[11], // W_pred
      (const float*)d_in[12], // b_pred
      (float*)d_out);
}